// Round 8
// baseline (267.629 us; speedup 1.0000x reference)
//
#include <hip/hip_runtime.h>
#include <hip/hip_fp16.h>

// Problem constants: B=2, T=32, H=64, W=64, C=64, KT=5, K=7. Circular dims pow2 -> & masks.
#define PLANE (64 * 64 * 64)          // H*W*C elements per (b,t)
#define NELEM 16777216                // B*T*H*W*C

typedef _Float16 f16x8 __attribute__((ext_vector_type(8)));
typedef _Float16 h2v  __attribute__((ext_vector_type(2)));
typedef float f32x4 __attribute__((ext_vector_type(4)));

// Guaranteed-packed f16 math (VOP3P). Register-only asm: deps tracked via constraints.
static __device__ __forceinline__ void pk_fma(uint& d, uint a, uint b) {
    asm("v_pk_fma_f16 %0, %1, %2, %0" : "+v"(d) : "v"(a), "v"(b));
}

// ---------------- fused dual projection GEMM (MFMA f16) ----------------
__global__ __launch_bounds__(256) void proj2_kernel(
    const float* __restrict__ x,
    const float* __restrict__ wg, const float* __restrict__ bg,
    const float* __restrict__ wh, const float* __restrict__ bh,
    _Float16* __restrict__ pg, _Float16* __restrict__ ph)
{
    __shared__ __align__(16) _Float16 sX[128 * 64];     // rows, 16B-chunk XOR swizzle
    __shared__ __align__(16) _Float16 sWT[2][64 * 64];  // [mat][d][c] transposed, swizzled
    const int tid = threadIdx.x;
    const long long row0 = (long long)blockIdx.x * 128;

    #pragma unroll
    for (int kci = 0; kci < 4; ++kci) {
        const int chunk = tid + kci * 256;
        const int r = chunk >> 3, q = chunk & 7;
        const float* gp = x + (row0 + r) * 64 + q * 8;
        const float4 v0 = *reinterpret_cast<const float4*>(gp);
        const float4 v1 = *reinterpret_cast<const float4*>(gp + 4);
        f16x8 hv;
        hv[0] = (_Float16)v0.x; hv[1] = (_Float16)v0.y; hv[2] = (_Float16)v0.z; hv[3] = (_Float16)v0.w;
        hv[4] = (_Float16)v1.x; hv[5] = (_Float16)v1.y; hv[6] = (_Float16)v1.z; hv[7] = (_Float16)v1.w;
        *reinterpret_cast<f16x8*>(&sX[r * 64 + ((q ^ (r & 7)) * 8)]) = hv;
    }
    {
        const int d = tid & 63;
        const int cb = (tid >> 6) * 16;
        #pragma unroll
        for (int i = 0; i < 16; ++i) {
            const int c = cb + i;
            const int off = d * 64 + (((c >> 3) ^ (d & 7)) * 8) + (c & 7);
            sWT[0][off] = (_Float16)wg[c * 64 + d];
            sWT[1][off] = (_Float16)wh[c * 64 + d];
        }
    }
    __syncthreads();

    const int wv = tid >> 6, lm = tid & 15, lg = (tid & 63) >> 4;
    f16x8 bf[2][4][2];                       // [mat][ntile][kstep]
    #pragma unroll
    for (int nt = 0; nt < 4; ++nt) {
        const int d = nt * 16 + lm;
        #pragma unroll
        for (int s = 0; s < 2; ++s) {
            const int off = d * 64 + (((s * 4 + lg) ^ (d & 7)) * 8);
            bf[0][nt][s] = *reinterpret_cast<const f16x8*>(&sWT[0][off]);
            bf[1][nt][s] = *reinterpret_cast<const f16x8*>(&sWT[1][off]);
        }
    }
    f32x4 acc[2][2][4];                      // [mat][mtile][ntile]
    #pragma unroll
    for (int m = 0; m < 2; ++m)
        #pragma unroll
        for (int mt = 0; mt < 2; ++mt)
            #pragma unroll
            for (int nt = 0; nt < 4; ++nt)
                acc[m][mt][nt] = (f32x4){0.f, 0.f, 0.f, 0.f};

    #pragma unroll
    for (int mt = 0; mt < 2; ++mt) {
        const int r = wv * 32 + mt * 16 + lm;
        const f16x8 a0 = *reinterpret_cast<const f16x8*>(&sX[r * 64 + ((lg ^ (r & 7)) * 8)]);
        const f16x8 a1 = *reinterpret_cast<const f16x8*>(&sX[r * 64 + (((4 + lg) ^ (r & 7)) * 8)]);
        #pragma unroll
        for (int nt = 0; nt < 4; ++nt) {
            acc[0][mt][nt] = __builtin_amdgcn_mfma_f32_16x16x32_f16(a0, bf[0][nt][0], acc[0][mt][nt], 0, 0, 0);
            acc[0][mt][nt] = __builtin_amdgcn_mfma_f32_16x16x32_f16(a1, bf[0][nt][1], acc[0][mt][nt], 0, 0, 0);
            acc[1][mt][nt] = __builtin_amdgcn_mfma_f32_16x16x32_f16(a0, bf[1][nt][0], acc[1][mt][nt], 0, 0, 0);
            acc[1][mt][nt] = __builtin_amdgcn_mfma_f32_16x16x32_f16(a1, bf[1][nt][1], acc[1][mt][nt], 0, 0, 0);
        }
    }
    #pragma unroll
    for (int nt = 0; nt < 4; ++nt) {
        const int col = nt * 16 + lm;
        const float bgv = bg[col], bhv = bh[col];
        #pragma unroll
        for (int mt = 0; mt < 2; ++mt) {
            const long long rb = row0 + wv * 32 + mt * 16 + lg * 4;
            #pragma unroll
            for (int i = 0; i < 4; ++i) {
                pg[(rb + i) * 64 + col] = (_Float16)(acc[0][mt][nt][i] + bgv);
                ph[(rb + i) * 64 + col] = (_Float16)(acc[1][mt][nt][i] + bhv);
            }
        }
    }
}

// ---------------- tap pre-convert: f32 kernels -> packed f16 pair table ----------------
// taps[((mat*32 + pglob)*35 + kt*7+kh)*8 + kw] = (f16 k[2p][tap], f16 k[2p+1][tap])
__global__ __launch_bounds__(256) void tapconv_kernel(
    const float* __restrict__ gk, const float* __restrict__ hk, uint* __restrict__ taps)
{
    const int i = blockIdx.x * 256 + threadIdx.x;   // [0, 17920)
    if (i >= 17920) return;
    const int kw = i & 7;
    int r = i >> 3;
    const int kth = r % 35;  r /= 35;               // kt*7+kh
    const int p = r & 31;
    const int mat = r >> 5;
    if (kw >= 7) { taps[i] = 0u; return; }
    const float* K = mat ? hk : gk;
    const int tap = kth * 7 + kw;                   // == kt*49 + kh*7 + kw
    h2v hv;
    hv[0] = (_Float16)K[(2 * p) * 245 + tap];
    hv[1] = (_Float16)K[(2 * p + 1) * 245 + tap];
    taps[i] = __builtin_bit_cast(uint, hv);
}

// ---------------- depthwise circular 3D conv, 8-wave block, packed-asm f16 ----------------
// Block = 512 thr (8 waves). Wave w owns channels c0=w*8 (4 pairs), same 16x16 spatial tile
// -> every 128B output line fully written by one block (kills write amplification).
// Input tile wave-private in LDS (8832B/wave, 70.6KB/block -> 2 blocks/CU, 4 waves/SIMD).
// amdgpu_waves_per_eu(4,4) pins the occupancy target so the allocator may use the full
// ~128-VGPR budget instead of spilling to chase 8 waves/EU it can never reach (LDS-capped).
// Taps from f16 global table (L2-resident) via overwrite-safe ring-of-4. Zero barriers.
// Chunked XCD swizzle, (wb,hb) innermost then t: rolling 5-plane window per XCD L2.
__global__ __attribute__((amdgpu_waves_per_eu(4, 4))) __launch_bounds__(512) void conv3d_dual_kernel(
    const _Float16* __restrict__ inG, _Float16* __restrict__ outG,
    const _Float16* __restrict__ inH, _Float16* __restrict__ outH,
    const uint* __restrict__ taps)
{
    __shared__ __align__(16) uint sIn[8 * 2208];    // 70656 B

    const int bid = (int)blockIdx.x;                // 0..2047
    // chunked XCD swizzle: xcd = bid&7 processes contiguous logical range
    const int l = ((bid & 7) << 8) | (bid >> 3);
    const int wb = l & 3;
    const int hb = (l >> 2) & 3;
    const int t  = (l >> 4) & 31;
    const int b  = (l >> 9) & 1;
    const int mat = l >> 10;
    const int wave = threadIdx.x >> 6;
    const int lane = threadIdx.x & 63;
    const int h0 = hb * 16, w0 = wb * 16, c0 = wave * 8;

    const _Float16* in = mat ? inH : inG;
    _Float16* out      = mat ? outH : outG;

    uint* mIn = sIn + wave * 2208;

    // per-thread staging addresses: 8 chunks of 8ch (uint4) over the 22x22 halo
    int soff[8], loff[8];
    #pragma unroll
    for (int it = 0; it < 8; ++it) {
        int c = it * 64 + lane;
        int pos = c > 483 ? 483 : c;
        const int ii = pos / 22, jj = pos - ii * 22;
        const int gh = (h0 - 3 + ii) & 63, gw = (w0 - 3 + jj) & 63;
        soff[it] = (gh * 64 + gw) * 64 + c0;
        loff[it] = ii * 24 + jj;
    }

    const int p  = lane & 3;
    const int iq = (lane >> 2) & 3;
    const int wq = lane >> 4;
    const int rowbase = p * 552 + wq * 4;
    const uint* tbase = taps + ((mat * 32 + wave * 4 + p) * 35) * 8;

    const _Float16* base = in + (long long)b * 32 * PLANE;

    uint4 ld[8];
    {
        const _Float16* pl = base + (long long)((t + 2) & 31) * PLANE;
        #pragma unroll
        for (int it = 0; it < 8; ++it)
            ld[it] = *reinterpret_cast<const uint4*>(pl + soff[it]);
    }

    uint tot[4][4];
    #pragma unroll
    for (int o = 0; o < 4; ++o)
        #pragma unroll
        for (int j = 0; j < 4; ++j) tot[o][j] = 0u;

    #pragma unroll 1
    for (int kt = 0; kt < 5; ++kt) {
        // write staged plane (wave-synchronous; DS in-order, no barrier)
        #pragma unroll
        for (int it = 0; it < 8; ++it) {
            const int a = loff[it];
            mIn[a]           = ld[it].x;
            mIn[a + 552]     = ld[it].y;
            mIn[a + 2 * 552] = ld[it].z;
            mIn[a + 3 * 552] = ld[it].w;
        }
        // prefetch next plane while computing this one (regs now available: no spill)
        if (kt < 4) {
            const _Float16* pl = base + (long long)((t - kt + 1) & 31) * PLANE;
            #pragma unroll
            for (int it = 0; it < 8; ++it)
                ld[it] = *reinterpret_cast<const uint4*>(pl + soff[it]);
        }

        uint kv[4][8];                      // tap ring: kh -> slot kh&3 (overwrite-safe)
        const uint* tkt = tbase + kt * 56;  // (kt*7+kh)*8 layout

        #pragma unroll
        for (int rr = 0; rr < 10; ++rr) {
            if (rr <= 6) {                  // load taps for kh=6-rr (first use this rr, o=0)
                const int kh = 6 - rr;
                const uint4 k0 = *reinterpret_cast<const uint4*>(tkt + kh * 8);
                const uint4 k1 = *reinterpret_cast<const uint4*>(tkt + kh * 8 + 4);
                kv[kh & 3][0] = k0.x; kv[kh & 3][1] = k0.y;
                kv[kh & 3][2] = k0.z; kv[kh & 3][3] = k0.w;
                kv[kh & 3][4] = k1.x; kv[kh & 3][5] = k1.y;
                kv[kh & 3][6] = k1.z; kv[kh & 3][7] = k1.w;
            }
            // load input row ii = 4*iq + rr, cols wq*4 .. wq*4+11 (10 used)
            const uint* rp = &mIn[rowbase + (4 * iq + rr) * 24];
            const uint4 r0 = *reinterpret_cast<const uint4*>(rp);
            const uint4 r1 = *reinterpret_cast<const uint4*>(rp + 4);
            const uint4 r2 = *reinterpret_cast<const uint4*>(rp + 8);
            uint row[12];
            row[0] = r0.x; row[1] = r0.y; row[2]  = r0.z; row[3]  = r0.w;
            row[4] = r1.x; row[5] = r1.y; row[6]  = r1.z; row[7]  = r1.w;
            row[8] = r2.x; row[9] = r2.y; row[10] = r2.z; row[11] = r2.w;

            #pragma unroll
            for (int o = 0; o < 4; ++o) {
                const int kh = o + 6 - rr;
                if (kh < 0 || kh > 6) continue;
                #pragma unroll
                for (int kw = 0; kw < 7; ++kw)
                    #pragma unroll
                    for (int j = 0; j < 4; ++j)
                        pk_fma(tot[o][j], kv[kh & 3][kw], row[j + 6 - kw]);
            }
        }
    }

    _Float16* ob = out + (long long)b * 32 * PLANE + (long long)t * PLANE;
    #pragma unroll
    for (int o = 0; o < 4; ++o) {
        #pragma unroll
        for (int j = 0; j < 4; ++j) {
            _Float16* dst = ob + (((h0 + 4 * iq + o) * 64 + w0 + wq * 4 + j) * 64 + c0 + 2 * p);
            *reinterpret_cast<uint*>(dst) = tot[o][j];
        }
    }
}

// ---------------- minGRU scan over T (f32 math, f16 I/O) ----------------
__global__ __launch_bounds__(256) void scan_kernel(
    const __half2* __restrict__ gs, const __half2* __restrict__ hs, __half2* __restrict__ hout)
{
    const int tid = blockIdx.x * 256 + threadIdx.x;    // 0..262143 half2 lanes
    const int b = tid >> 17;
    const int q = tid & 131071;
    const long long bb = (long long)b * 32 * 131072 + q;
    float h0 = 0.f, h1 = 0.f;
    for (int t = 0; t < 32; ++t) {
        const long long a = bb + (long long)t * 131072;
        const float2 g  = __half22float2(gs[a]);
        const float2 hv = __half22float2(hs[a]);
        const float z0 = 1.f / (1.f + __expf(-g.x));
        const float z1 = 1.f / (1.f + __expf(-g.y));
        h0 = fmaf(1.f - z0, h0, z0 * fmaf(hv.x, hv.x, 1e-6f));
        h1 = fmaf(1.f - z1, h1, z1 * fmaf(hv.y, hv.y, 1e-6f));
        hout[a] = __floats2half2_rn(h0, h1);
    }
}

// ---------------- output GEMM (MFMA f16, f32 out) ----------------
__global__ __launch_bounds__(256) void outgemm_kernel(
    const _Float16* __restrict__ hin, const float* __restrict__ w,
    const float* __restrict__ bias, float* __restrict__ out)
{
    __shared__ __align__(16) _Float16 sX[128 * 64];
    __shared__ __align__(16) _Float16 sWT[64 * 64];
    const int tid = threadIdx.x;
    const long long row0 = (long long)blockIdx.x * 128;

    #pragma unroll
    for (int kci = 0; kci < 4; ++kci) {
        const int chunk = tid + kci * 256;
        const int r = chunk >> 3, q = chunk & 7;
        const f16x8 hv = *reinterpret_cast<const f16x8*>(hin + (row0 + r) * 64 + q * 8);
        *reinterpret_cast<f16x8*>(&sX[r * 64 + ((q ^ (r & 7)) * 8)]) = hv;
    }
    {
        const int d = tid & 63;
        const int cb = (tid >> 6) * 16;
        #pragma unroll
        for (int i = 0; i < 16; ++i) {
            const int c = cb + i;
            sWT[d * 64 + (((c >> 3) ^ (d & 7)) * 8) + (c & 7)] = (_Float16)w[c * 64 + d];
        }
    }
    __syncthreads();

    const int wv = tid >> 6, lm = tid & 15, lg = (tid & 63) >> 4;
    f16x8 bf[4][2];
    #pragma unroll
    for (int nt = 0; nt < 4; ++nt) {
        const int d = nt * 16 + lm;
        #pragma unroll
        for (int s = 0; s < 2; ++s)
            bf[nt][s] = *reinterpret_cast<const f16x8*>(&sWT[d * 64 + (((s * 4 + lg) ^ (d & 7)) * 8)]);
    }
    f32x4 acc[2][4];
    #pragma unroll
    for (int mt = 0; mt < 2; ++mt)
        #pragma unroll
        for (int nt = 0; nt < 4; ++nt)
            acc[mt][nt] = (f32x4){0.f, 0.f, 0.f, 0.f};

    #pragma unroll
    for (int mt = 0; mt < 2; ++mt) {
        const int r = wv * 32 + mt * 16 + lm;
        const f16x8 a0 = *reinterpret_cast<const f16x8*>(&sX[r * 64 + ((lg ^ (r & 7)) * 8)]);
        const f16x8 a1 = *reinterpret_cast<const f16x8*>(&sX[r * 64 + (((4 + lg) ^ (r & 7)) * 8)]);
        #pragma unroll
        for (int nt = 0; nt < 4; ++nt) {
            acc[mt][nt] = __builtin_amdgcn_mfma_f32_16x16x32_f16(a0, bf[nt][0], acc[mt][nt], 0, 0, 0);
            acc[mt][nt] = __builtin_amdgcn_mfma_f32_16x16x32_f16(a1, bf[nt][1], acc[mt][nt], 0, 0, 0);
        }
    }
    #pragma unroll
    for (int nt = 0; nt < 4; ++nt) {
        const int col = nt * 16 + lm;
        const float bv = bias[col];
        #pragma unroll
        for (int mt = 0; mt < 2; ++mt) {
            const long long rb = row0 + wv * 32 + mt * 16 + lg * 4;
            #pragma unroll
            for (int i = 0; i < 4; ++i)
                out[(rb + i) * 64 + col] = acc[mt][nt][i] + bv;
        }
    }
}

extern "C" void kernel_launch(void* const* d_in, const int* in_sizes, int n_in,
                              void* d_out, int out_size, void* d_ws, size_t ws_size,
                              hipStream_t stream)
{
    const float* x  = (const float*)d_in[0];
    const float* gw = (const float*)d_in[1];
    const float* gb = (const float*)d_in[2];
    const float* hw = (const float*)d_in[3];
    const float* hb = (const float*)d_in[4];
    const float* gk = (const float*)d_in[5];
    const float* hk = (const float*)d_in[6];
    const float* ow = (const float*)d_in[7];
    const float* ob = (const float*)d_in[8];

    _Float16* W1 = (_Float16*)d_ws;          // 33.5 MB each
    _Float16* W2 = W1 + NELEM;
    _Float16* W3 = W2 + NELEM;
    uint* taps   = (uint*)(W3 + NELEM);      // 71.7 KB tap table (both matrices)

    // 0) tap table (tiny)
    tapconv_kernel<<<70, 256, 0, stream>>>(gk, hk, taps);
    // 1) proj: x -> W1 (gate_proj f16), W2 (hidden_proj f16)
    proj2_kernel<<<2048, 256, 0, stream>>>(x, gw, gb, hw, hb, W1, W2);
    // 2+3) both convs, all 64ch per block: W1 -> W3 (gate), W2 -> d_out scratch (hidden)
    conv3d_dual_kernel<<<2048, 512, 0, stream>>>(W1, W3, W2, (_Float16*)d_out, taps);
    // 4) scan: (W3 gate, d_out hidden) -> W2
    scan_kernel<<<1024, 256, 0, stream>>>((const __half2*)W3, (const __half2*)d_out, (__half2*)W2);
    // 5) out GEMM: W2 -> d_out (f32, overwrites scratch)
    outgemm_kernel<<<2048, 256, 0, stream>>>(W2, ow, ob, (float*)d_out);
}

// Round 9
// 226.835 us; speedup vs baseline: 1.1798x; 1.1798x over previous
//
#include <hip/hip_runtime.h>
#include <hip/hip_fp16.h>

// Problem constants: B=2, T=32, H=64, W=64, C=64, KT=5, K=7. Circular dims pow2 -> & masks.
// Intermediates are CHANNEL-MAJOR: uint array [pair=c/2][b][t][h][w], pair stride 262144 uints.
#define NELEM 16777216

typedef _Float16 f16x8 __attribute__((ext_vector_type(8)));
typedef _Float16 h2v  __attribute__((ext_vector_type(2)));
typedef float f32x4 __attribute__((ext_vector_type(4)));

static __device__ __forceinline__ void pk_fma(uint& d, uint a, uint b) {
    asm("v_pk_fma_f16 %0, %1, %2, %0" : "+v"(d) : "v"(a), "v"(b));
}

// ---------------- fused dual projection GEMM (MFMA f16, channel-major out) ----------------
__global__ __launch_bounds__(256) void proj2_kernel(
    const float* __restrict__ x,
    const float* __restrict__ wg, const float* __restrict__ bg,
    const float* __restrict__ wh, const float* __restrict__ bh,
    uint* __restrict__ pg, uint* __restrict__ ph)
{
    __shared__ __align__(16) _Float16 sX[128 * 64];
    __shared__ __align__(16) _Float16 sWT[2][64 * 64];
    const int tid = threadIdx.x;
    const int row0 = (int)blockIdx.x * 128;

    #pragma unroll
    for (int kci = 0; kci < 4; ++kci) {
        const int chunk = tid + kci * 256;
        const int r = chunk >> 3, q = chunk & 7;
        const float* gp = x + (long long)(row0 + r) * 64 + q * 8;
        const float4 v0 = *reinterpret_cast<const float4*>(gp);
        const float4 v1 = *reinterpret_cast<const float4*>(gp + 4);
        f16x8 hv;
        hv[0] = (_Float16)v0.x; hv[1] = (_Float16)v0.y; hv[2] = (_Float16)v0.z; hv[3] = (_Float16)v0.w;
        hv[4] = (_Float16)v1.x; hv[5] = (_Float16)v1.y; hv[6] = (_Float16)v1.z; hv[7] = (_Float16)v1.w;
        *reinterpret_cast<f16x8*>(&sX[r * 64 + ((q ^ (r & 7)) * 8)]) = hv;
    }
    {
        const int d = tid & 63;
        const int cb = (tid >> 6) * 16;
        #pragma unroll
        for (int i = 0; i < 16; ++i) {
            const int c = cb + i;
            const int off = d * 64 + (((c >> 3) ^ (d & 7)) * 8) + (c & 7);
            sWT[0][off] = (_Float16)wg[c * 64 + d];
            sWT[1][off] = (_Float16)wh[c * 64 + d];
        }
    }
    __syncthreads();

    const int wv = tid >> 6, lm = tid & 15, lg = (tid & 63) >> 4;
    f16x8 bf[2][4][2];
    #pragma unroll
    for (int nt = 0; nt < 4; ++nt) {
        const int d = nt * 16 + lm;
        #pragma unroll
        for (int s = 0; s < 2; ++s) {
            const int off = d * 64 + (((s * 4 + lg) ^ (d & 7)) * 8);
            bf[0][nt][s] = *reinterpret_cast<const f16x8*>(&sWT[0][off]);
            bf[1][nt][s] = *reinterpret_cast<const f16x8*>(&sWT[1][off]);
        }
    }
    f32x4 acc[2][2][4];
    #pragma unroll
    for (int m = 0; m < 2; ++m)
        #pragma unroll
        for (int mt = 0; mt < 2; ++mt)
            #pragma unroll
            for (int nt = 0; nt < 4; ++nt)
                acc[m][mt][nt] = (f32x4){0.f, 0.f, 0.f, 0.f};

    #pragma unroll
    for (int mt = 0; mt < 2; ++mt) {
        const int r = wv * 32 + mt * 16 + lm;
        const f16x8 a0 = *reinterpret_cast<const f16x8*>(&sX[r * 64 + ((lg ^ (r & 7)) * 8)]);
        const f16x8 a1 = *reinterpret_cast<const f16x8*>(&sX[r * 64 + (((4 + lg) ^ (r & 7)) * 8)]);
        #pragma unroll
        for (int nt = 0; nt < 4; ++nt) {
            acc[0][mt][nt] = __builtin_amdgcn_mfma_f32_16x16x32_f16(a0, bf[0][nt][0], acc[0][mt][nt], 0, 0, 0);
            acc[0][mt][nt] = __builtin_amdgcn_mfma_f32_16x16x32_f16(a1, bf[0][nt][1], acc[0][mt][nt], 0, 0, 0);
            acc[1][mt][nt] = __builtin_amdgcn_mfma_f32_16x16x32_f16(a0, bf[1][nt][0], acc[1][mt][nt], 0, 0, 0);
            acc[1][mt][nt] = __builtin_amdgcn_mfma_f32_16x16x32_f16(a1, bf[1][nt][1], acc[1][mt][nt], 0, 0, 0);
        }
    }
    // epilogue: pair lanes (lm, lm^1) via shfl, even lane stores uint4 (4 rows) channel-major
    #pragma unroll
    for (int nt = 0; nt < 4; ++nt) {
        const int col = nt * 16 + lm;
        const int pr  = col >> 1;
        const float bgv = bg[col], bhv = bh[col];
        #pragma unroll
        for (int mt = 0; mt < 2; ++mt) {
            const int rb = row0 + wv * 32 + mt * 16 + lg * 4;
            uint pk0[4], pk1[4];
            #pragma unroll
            for (int i = 0; i < 4; ++i) {
                const float v0 = acc[0][mt][nt][i] + bgv;
                const float p0 = __shfl_xor(v0, 1);
                const float v1 = acc[1][mt][nt][i] + bhv;
                const float p1 = __shfl_xor(v1, 1);
                h2v a, c;
                a[0] = (_Float16)((lm & 1) ? p0 : v0); a[1] = (_Float16)((lm & 1) ? v0 : p0);
                c[0] = (_Float16)((lm & 1) ? p1 : v1); c[1] = (_Float16)((lm & 1) ? v1 : p1);
                pk0[i] = __builtin_bit_cast(uint, a);
                pk1[i] = __builtin_bit_cast(uint, c);
            }
            if (!(lm & 1)) {
                *reinterpret_cast<uint4*>(pg + pr * 262144 + rb) = make_uint4(pk0[0], pk0[1], pk0[2], pk0[3]);
                *reinterpret_cast<uint4*>(ph + pr * 262144 + rb) = make_uint4(pk1[0], pk1[1], pk1[2], pk1[3]);
            }
        }
    }
}

// ---------------- tap pre-convert: f32 kernels -> packed f16 pair table ----------------
// taps[((mat*32 + p)*35 + kt*7+kh)*8 + kw]
__global__ __launch_bounds__(256) void tapconv_kernel(
    const float* __restrict__ gk, const float* __restrict__ hk, uint* __restrict__ taps)
{
    const int i = blockIdx.x * 256 + threadIdx.x;   // [0, 17920)
    if (i >= 17920) return;
    const int kw = i & 7;
    int r = i >> 3;
    const int kth = r % 35;  r /= 35;
    const int p = r & 31;
    const int mat = r >> 5;
    if (kw >= 7) { taps[i] = 0u; return; }
    const float* K = mat ? hk : gk;
    const int tap = kth * 7 + kw;
    h2v hv;
    hv[0] = (_Float16)K[(2 * p) * 245 + tap];
    hv[1] = (_Float16)K[(2 * p + 1) * 245 + tap];
    taps[i] = __builtin_bit_cast(uint, hv);
}

// ---------------- depthwise circular 3D conv: 1 pair/wave, 32x32 tile, channel-major ----------------
// Block = 256 thr (4 waves), each wave one channel-pair over one 32x32 spatial tile.
// LDS/wave: 38x40 uint tile (1520) + 280 taps = 1800 uints (7.2KB); block 28.8KB -> 5 blocks/CU
// = 20 waves/CU = 5 waves/SIMD. Zero barriers (wave-private LDS). Taps broadcast from LDS.
// Lane = (iy,ix) 8x8, computes 4h x 4w h2 outputs. Output = full 128B lines.
__global__ __launch_bounds__(256, 5) void conv3d_dual_kernel(
    const uint* __restrict__ inG, uint* __restrict__ outG,
    const uint* __restrict__ inH, uint* __restrict__ outH,
    const uint* __restrict__ taps)
{
    __shared__ __align__(16) uint sAll[4 * 1800];   // 28800 B

    const int bid = (int)blockIdx.x;                // 0..4095
    const int l = ((bid & 7) << 9) | (bid >> 3);    // chunked XCD swizzle
    const int tile = l & 3;
    const int pgrp = (l >> 2) & 7;
    const int t    = (l >> 5) & 31;
    const int b    = (l >> 10) & 1;
    const int mat  = (l >> 11) & 1;
    const int wave = threadIdx.x >> 6;
    const int lane = threadIdx.x & 63;
    const int h0 = (tile >> 1) * 32, w0 = (tile & 1) * 32;
    const int pair = pgrp * 4 + wave;

    const uint* in = mat ? inH : inG;
    uint* out      = mat ? outH : outG;

    uint* tileL = sAll + wave * 1800;
    uint* tapL  = tileL + 1520;

    // stage this pair's taps once (layout already [kt*56 + kh*8 + kw], kw=7 zero-padded)
    const uint* gt = taps + (mat * 32 + pair) * 280;
    for (int i = lane; i < 280; i += 64) tapL[i] = gt[i];

    const int iy = lane >> 3, ix = lane & 7;

    uint tot[4][4];
    #pragma unroll
    for (int o = 0; o < 4; ++o)
        #pragma unroll
        for (int j = 0; j < 4; ++j) tot[o][j] = 0u;

    #pragma unroll 1
    for (int kt = 0; kt < 5; ++kt) {
        const int tin = (t - kt + 2) & 31;
        const uint2* pin = reinterpret_cast<const uint2*>(in) +
                           (pair * 131072 + (b * 32 + tin) * 2048);
        // stage 38 rows x 40 cols (uint2 chunks, W-window starts at even w0-4, wrap-safe)
        #pragma unroll
        for (int ro = 0; ro < 12; ++ro) {
            const int idx = ro * 64 + lane;
            if (idx < 760) {
                const int r  = (idx * 205) >> 12;       // idx/20
                const int c2 = idx - r * 20;
                const int gh = (h0 - 3 + r) & 63;
                const int uc = ((w0 >> 1) - 2 + c2) & 31;
                const uint2 v = pin[gh * 32 + uc];
                *reinterpret_cast<uint2*>(&tileL[r * 40 + c2 * 2]) = v;
            }
        }

        const uint* tkt = tapL + kt * 56;
        uint kv[4][8];                      // tap ring: kh -> slot kh&3 (overwrite-safe)

        #pragma unroll
        for (int rr = 0; rr < 10; ++rr) {
            if (rr <= 6) {                  // broadcast-load taps for kh=6-rr (first use this rr)
                const int kh = 6 - rr;
                const uint4 k0 = *reinterpret_cast<const uint4*>(tkt + kh * 8);
                const uint4 k1 = *reinterpret_cast<const uint4*>(tkt + kh * 8 + 4);
                kv[kh & 3][0] = k0.x; kv[kh & 3][1] = k0.y;
                kv[kh & 3][2] = k0.z; kv[kh & 3][3] = k0.w;
                kv[kh & 3][4] = k1.x; kv[kh & 3][5] = k1.y;
                kv[kh & 3][6] = k1.z; kv[kh & 3][7] = k1.w;
            }
            // input row window: 12 h2 at window cols [4ix, 4ix+11], row 4iy+rr
            const uint* rp = &tileL[(4 * iy + rr) * 40 + 4 * ix];
            const uint4 r0 = *reinterpret_cast<const uint4*>(rp);
            const uint4 r1 = *reinterpret_cast<const uint4*>(rp + 4);
            const uint4 r2 = *reinterpret_cast<const uint4*>(rp + 8);
            uint row[12];
            row[0] = r0.x; row[1] = r0.y; row[2]  = r0.z; row[3]  = r0.w;
            row[4] = r1.x; row[5] = r1.y; row[6]  = r1.z; row[7]  = r1.w;
            row[8] = r2.x; row[9] = r2.y; row[10] = r2.z; row[11] = r2.w;

            #pragma unroll
            for (int o = 0; o < 4; ++o) {
                const int kh = o + 6 - rr;
                if (kh < 0 || kh > 6) continue;
                #pragma unroll
                for (int kw = 0; kw < 7; ++kw)
                    #pragma unroll
                    for (int j = 0; j < 4; ++j)
                        pk_fma(tot[o][j], kv[kh & 3][kw], row[j + 7 - kw]);
            }
        }
    }

    uint* ob = out + pair * 262144 + (b * 32 + t) * 4096;
    #pragma unroll
    for (int o = 0; o < 4; ++o)
        *reinterpret_cast<uint4*>(ob + (h0 + 4 * iy + o) * 64 + (w0 + 4 * ix)) =
            make_uint4(tot[o][0], tot[o][1], tot[o][2], tot[o][3]);
}

// ---------------- minGRU scan over T (f32 math, channel-major h2 I/O) ----------------
__global__ __launch_bounds__(256) void scan_kernel(
    const uint* __restrict__ gs, const uint* __restrict__ hs, uint* __restrict__ hout)
{
    const int tid = blockIdx.x * 256 + threadIdx.x;    // 0..262143
    const int base = (tid >> 12) * 131072 + (tid & 4095);
    float h0 = 0.f, h1 = 0.f;
    for (int t = 0; t < 32; ++t) {
        const int a = base + t * 4096;
        const float2 g  = __half22float2(__builtin_bit_cast(__half2, gs[a]));
        const float2 hv = __half22float2(__builtin_bit_cast(__half2, hs[a]));
        const float z0 = 1.f / (1.f + __expf(-g.x));
        const float z1 = 1.f / (1.f + __expf(-g.y));
        h0 = fmaf(1.f - z0, h0, z0 * fmaf(hv.x, hv.x, 1e-6f));
        h1 = fmaf(1.f - z1, h1, z1 * fmaf(hv.y, hv.y, 1e-6f));
        hout[a] = __builtin_bit_cast(uint, __floats2half2_rn(h0, h1));
    }
}

// ---------------- output GEMM (MFMA f16, channel-major in, f32 row-major out) ----------------
__global__ __launch_bounds__(256) void outgemm_kernel(
    const uint* __restrict__ hin, const float* __restrict__ w,
    const float* __restrict__ bias, float* __restrict__ out)
{
    __shared__ __align__(16) uint sXu[128 * 36];        // rows x 32 pairs (stride 36: 16B-aligned)
    __shared__ __align__(16) _Float16 sWT[64 * 64];
    const int tid = threadIdx.x;
    const int row0 = (int)blockIdx.x * 128;

    {   // stage 128 rows x 32 pairs from channel-major
        const int pr = tid >> 3, k = tid & 7;
        const uint* src = hin + pr * 262144 + row0 + k * 16;
        #pragma unroll
        for (int q = 0; q < 4; ++q) {
            const uint4 v = *reinterpret_cast<const uint4*>(src + q * 4);
            sXu[(k * 16 + q * 4 + 0) * 36 + pr] = v.x;
            sXu[(k * 16 + q * 4 + 1) * 36 + pr] = v.y;
            sXu[(k * 16 + q * 4 + 2) * 36 + pr] = v.z;
            sXu[(k * 16 + q * 4 + 3) * 36 + pr] = v.w;
        }
    }
    {
        const int d = tid & 63;
        const int cb = (tid >> 6) * 16;
        #pragma unroll
        for (int i = 0; i < 16; ++i) {
            const int c = cb + i;
            sWT[d * 64 + (((c >> 3) ^ (d & 7)) * 8) + (c & 7)] = (_Float16)w[c * 64 + d];
        }
    }
    __syncthreads();

    const int wv = tid >> 6, lm = tid & 15, lg = (tid & 63) >> 4;
    f16x8 bf[4][2];
    #pragma unroll
    for (int nt = 0; nt < 4; ++nt) {
        const int d = nt * 16 + lm;
        #pragma unroll
        for (int s = 0; s < 2; ++s)
            bf[nt][s] = *reinterpret_cast<const f16x8*>(&sWT[d * 64 + (((s * 4 + lg) ^ (d & 7)) * 8)]);
    }
    f32x4 acc[2][4];
    #pragma unroll
    for (int mt = 0; mt < 2; ++mt)
        #pragma unroll
        for (int nt = 0; nt < 4; ++nt)
            acc[mt][nt] = (f32x4){0.f, 0.f, 0.f, 0.f};

    #pragma unroll
    for (int mt = 0; mt < 2; ++mt) {
        const int r = wv * 32 + mt * 16 + lm;
        const f16x8 a0 = *reinterpret_cast<const f16x8*>(&sXu[r * 36 + lg * 4]);
        const f16x8 a1 = *reinterpret_cast<const f16x8*>(&sXu[r * 36 + 16 + lg * 4]);
        #pragma unroll
        for (int nt = 0; nt < 4; ++nt) {
            acc[mt][nt] = __builtin_amdgcn_mfma_f32_16x16x32_f16(a0, bf[nt][0], acc[mt][nt], 0, 0, 0);
            acc[mt][nt] = __builtin_amdgcn_mfma_f32_16x16x32_f16(a1, bf[nt][1], acc[mt][nt], 0, 0, 0);
        }
    }
    #pragma unroll
    for (int nt = 0; nt < 4; ++nt) {
        const int col = nt * 16 + lm;
        const float bv = bias[col];
        #pragma unroll
        for (int mt = 0; mt < 2; ++mt) {
            const long long rb = row0 + wv * 32 + mt * 16 + lg * 4;
            #pragma unroll
            for (int i = 0; i < 4; ++i)
                out[(rb + i) * 64 + col] = acc[mt][nt][i] + bv;
        }
    }
}

extern "C" void kernel_launch(void* const* d_in, const int* in_sizes, int n_in,
                              void* d_out, int out_size, void* d_ws, size_t ws_size,
                              hipStream_t stream)
{
    const float* x  = (const float*)d_in[0];
    const float* gw = (const float*)d_in[1];
    const float* gb = (const float*)d_in[2];
    const float* hw = (const float*)d_in[3];
    const float* hb = (const float*)d_in[4];
    const float* gk = (const float*)d_in[5];
    const float* hk = (const float*)d_in[6];
    const float* ow = (const float*)d_in[7];
    const float* ob = (const float*)d_in[8];

    uint* W1 = (uint*)d_ws;                  // 33.5 MB each (channel-major h2)
    uint* W2 = W1 + NELEM / 2;
    uint* W3 = W2 + NELEM / 2;
    uint* taps = W3 + NELEM / 2;             // 71.7 KB tap table
    uint* Dsc = (uint*)d_out;                // hidden_spatial scratch (first 33.5MB of d_out)

    // 0) tap table
    tapconv_kernel<<<70, 256, 0, stream>>>(gk, hk, taps);
    // 1) proj: x -> W1 (gate_proj cm), W2 (hidden_proj cm)
    proj2_kernel<<<2048, 256, 0, stream>>>(x, gw, gb, hw, hb, W1, W2);
    // 2+3) dual conv: W1 -> W3 (gate_sp), W2 -> Dsc (hidden_sp)
    conv3d_dual_kernel<<<4096, 256, 0, stream>>>(W1, W3, W2, Dsc, taps);
    // 4) scan: (W3, Dsc) -> W1 (h, cm)
    scan_kernel<<<1024, 256, 0, stream>>>(W3, Dsc, W1);
    // 5) out GEMM: W1 -> d_out (f32 row-major, overwrites scratch)
    outgemm_kernel<<<2048, 256, 0, stream>>>(W1, ow, ob, (float*)d_out);
}

// Round 10
// 208.011 us; speedup vs baseline: 1.2866x; 1.0905x over previous
//
#include <hip/hip_runtime.h>
#include <hip/hip_fp16.h>

// Problem constants: B=2, T=32, H=64, W=64, C=64, KT=5, K=7. Circular dims pow2 -> & masks.
// Intermediates are CHANNEL-MAJOR: uint array [pair=c/2][b][t][h][w], pair stride 262144 uints.
#define NELEM 16777216

typedef _Float16 f16x8 __attribute__((ext_vector_type(8)));
typedef _Float16 h2v  __attribute__((ext_vector_type(2)));
typedef float f32x4 __attribute__((ext_vector_type(4)));

// packed f16 fma, tap in SGPR (src0 may be SGPR in VOP3P; max-1-SGPR rule satisfied)
static __device__ __forceinline__ void pk_fma_sv(uint& d, uint a_s, uint b_v) {
    asm("v_pk_fma_f16 %0, %1, %2, %0" : "+v"(d) : "s"(a_s), "v"(b_v));
}

// ---------------- fused dual projection GEMM (MFMA f16, channel-major out) ----------------
__global__ __launch_bounds__(256) void proj2_kernel(
    const float* __restrict__ x,
    const float* __restrict__ wg, const float* __restrict__ bg,
    const float* __restrict__ wh, const float* __restrict__ bh,
    uint* __restrict__ pg, uint* __restrict__ ph)
{
    __shared__ __align__(16) _Float16 sX[128 * 64];
    __shared__ __align__(16) _Float16 sWT[2][64 * 64];
    const int tid = threadIdx.x;
    const int row0 = (int)blockIdx.x * 128;

    #pragma unroll
    for (int kci = 0; kci < 4; ++kci) {
        const int chunk = tid + kci * 256;
        const int r = chunk >> 3, q = chunk & 7;
        const float* gp = x + (long long)(row0 + r) * 64 + q * 8;
        const float4 v0 = *reinterpret_cast<const float4*>(gp);
        const float4 v1 = *reinterpret_cast<const float4*>(gp + 4);
        f16x8 hv;
        hv[0] = (_Float16)v0.x; hv[1] = (_Float16)v0.y; hv[2] = (_Float16)v0.z; hv[3] = (_Float16)v0.w;
        hv[4] = (_Float16)v1.x; hv[5] = (_Float16)v1.y; hv[6] = (_Float16)v1.z; hv[7] = (_Float16)v1.w;
        *reinterpret_cast<f16x8*>(&sX[r * 64 + ((q ^ (r & 7)) * 8)]) = hv;
    }
    {
        const int d = tid & 63;
        const int cb = (tid >> 6) * 16;
        #pragma unroll
        for (int i = 0; i < 16; ++i) {
            const int c = cb + i;
            const int off = d * 64 + (((c >> 3) ^ (d & 7)) * 8) + (c & 7);
            sWT[0][off] = (_Float16)wg[c * 64 + d];
            sWT[1][off] = (_Float16)wh[c * 64 + d];
        }
    }
    __syncthreads();

    const int wv = tid >> 6, lm = tid & 15, lg = (tid & 63) >> 4;
    f16x8 bf[2][4][2];
    #pragma unroll
    for (int nt = 0; nt < 4; ++nt) {
        const int d = nt * 16 + lm;
        #pragma unroll
        for (int s = 0; s < 2; ++s) {
            const int off = d * 64 + (((s * 4 + lg) ^ (d & 7)) * 8);
            bf[0][nt][s] = *reinterpret_cast<const f16x8*>(&sWT[0][off]);
            bf[1][nt][s] = *reinterpret_cast<const f16x8*>(&sWT[1][off]);
        }
    }
    f32x4 acc[2][2][4];
    #pragma unroll
    for (int m = 0; m < 2; ++m)
        #pragma unroll
        for (int mt = 0; mt < 2; ++mt)
            #pragma unroll
            for (int nt = 0; nt < 4; ++nt)
                acc[m][mt][nt] = (f32x4){0.f, 0.f, 0.f, 0.f};

    #pragma unroll
    for (int mt = 0; mt < 2; ++mt) {
        const int r = wv * 32 + mt * 16 + lm;
        const f16x8 a0 = *reinterpret_cast<const f16x8*>(&sX[r * 64 + ((lg ^ (r & 7)) * 8)]);
        const f16x8 a1 = *reinterpret_cast<const f16x8*>(&sX[r * 64 + (((4 + lg) ^ (r & 7)) * 8)]);
        #pragma unroll
        for (int nt = 0; nt < 4; ++nt) {
            acc[0][mt][nt] = __builtin_amdgcn_mfma_f32_16x16x32_f16(a0, bf[0][nt][0], acc[0][mt][nt], 0, 0, 0);
            acc[0][mt][nt] = __builtin_amdgcn_mfma_f32_16x16x32_f16(a1, bf[0][nt][1], acc[0][mt][nt], 0, 0, 0);
            acc[1][mt][nt] = __builtin_amdgcn_mfma_f32_16x16x32_f16(a0, bf[1][nt][0], acc[1][mt][nt], 0, 0, 0);
            acc[1][mt][nt] = __builtin_amdgcn_mfma_f32_16x16x32_f16(a1, bf[1][nt][1], acc[1][mt][nt], 0, 0, 0);
        }
    }
    // epilogue: pair lanes (lm, lm^1) via shfl, even lane stores uint4 (4 rows) channel-major
    #pragma unroll
    for (int nt = 0; nt < 4; ++nt) {
        const int col = nt * 16 + lm;
        const int pr  = col >> 1;
        const float bgv = bg[col], bhv = bh[col];
        #pragma unroll
        for (int mt = 0; mt < 2; ++mt) {
            const int rb = row0 + wv * 32 + mt * 16 + lg * 4;
            uint pk0[4], pk1[4];
            #pragma unroll
            for (int i = 0; i < 4; ++i) {
                const float v0 = acc[0][mt][nt][i] + bgv;
                const float p0 = __shfl_xor(v0, 1);
                const float v1 = acc[1][mt][nt][i] + bhv;
                const float p1 = __shfl_xor(v1, 1);
                h2v a, c;
                a[0] = (_Float16)((lm & 1) ? p0 : v0); a[1] = (_Float16)((lm & 1) ? v0 : p0);
                c[0] = (_Float16)((lm & 1) ? p1 : v1); c[1] = (_Float16)((lm & 1) ? v1 : p1);
                pk0[i] = __builtin_bit_cast(uint, a);
                pk1[i] = __builtin_bit_cast(uint, c);
            }
            if (!(lm & 1)) {
                *reinterpret_cast<uint4*>(pg + pr * 262144 + rb) = make_uint4(pk0[0], pk0[1], pk0[2], pk0[3]);
                *reinterpret_cast<uint4*>(ph + pr * 262144 + rb) = make_uint4(pk1[0], pk1[1], pk1[2], pk1[3]);
            }
        }
    }
}

// ---------------- tap pre-convert: f32 kernels -> packed f16 pair table ----------------
// taps[((mat*32 + p)*35 + kt*7+kh)*8 + kw], kw=7 zero-padded
__global__ __launch_bounds__(256) void tapconv_kernel(
    const float* __restrict__ gk, const float* __restrict__ hk, uint* __restrict__ taps)
{
    const int i = blockIdx.x * 256 + threadIdx.x;   // [0, 17920)
    if (i >= 17920) return;
    const int kw = i & 7;
    int r = i >> 3;
    const int kth = r % 35;  r /= 35;
    const int p = r & 31;
    const int mat = r >> 5;
    if (kw >= 7) { taps[i] = 0u; return; }
    const float* K = mat ? hk : gk;
    const int tap = kth * 7 + kw;
    h2v hv;
    hv[0] = (_Float16)K[(2 * p) * 245 + tap];
    hv[1] = (_Float16)K[(2 * p + 1) * 245 + tap];
    taps[i] = __builtin_bit_cast(uint, hv);
}

// ---------------- depthwise circular 3D conv: LDS-FREE, channel-major ----------------
// Wave = one channel-pair over one 32x32 tile; lane (iy,ix) computes 4h x 4w.
// Input window read DIRECTLY from global: 3x b128/lane/row; 8-lane groups are
// 128B-contiguous (1 line each), chunks 16B-aligned so circular W-wrap (&63 on
// 4-aligned cols) never straddles a chunk. Taps: wave-uniform SGPR loads
// (readfirstlane base) -> zero VGPR cost, pk_fma takes tap as SGPR src0.
// No LDS, no barriers -> occupancy VGPR-limited (target <=64 -> 8 waves/SIMD).
__global__ __launch_bounds__(256) void conv3d_dual_kernel(
    const uint* __restrict__ inG, uint* __restrict__ outG,
    const uint* __restrict__ inH, uint* __restrict__ outH,
    const uint* __restrict__ taps)
{
    const int bid = (int)blockIdx.x;                // 0..4095
    const int l = ((bid & 7) << 9) | (bid >> 3);    // chunked XCD swizzle (r9-proven)
    const int tile = l & 3;
    const int pgrp = (l >> 2) & 7;
    const int t    = (l >> 5) & 31;
    const int b    = (l >> 10) & 1;
    const int mat  = (l >> 11) & 1;
    const int wave = threadIdx.x >> 6;
    const int lane = threadIdx.x & 63;
    const int h0 = (tile >> 1) * 32, w0 = (tile & 1) * 32;
    const int pair = pgrp * 4 + wave;

    const uint* in = mat ? inH : inG;
    uint* out      = mat ? outH : outG;

    const int iy = lane >> 3, ix = lane & 7;

    // wave-uniform SGPR bases
    const int tapOff = __builtin_amdgcn_readfirstlane((mat * 32 + pair) * 280);
    const uint* tb = taps + tapOff;
    const int pbOff = __builtin_amdgcn_readfirstlane(pair * 262144 + b * 131072);

    // per-lane window chunk columns (uint idx, 4-aligned, circular)
    int colu[3];
    #pragma unroll
    for (int m = 0; m < 3; ++m) colu[m] = (w0 + 4 * ix - 4 + 4 * m) & 63;

    uint tot[4][4];
    #pragma unroll
    for (int o = 0; o < 4; ++o)
        #pragma unroll
        for (int j = 0; j < 4; ++j) tot[o][j] = 0u;

    #pragma unroll 1
    for (int kt = 0; kt < 5; ++kt) {
        const int tin = (t - kt + 2) & 31;
        const uint* pin = in + pbOff + tin * 4096;      // SGPR base
        const uint* tkt = tb + kt * 56;

        uint kv[7][8];                                  // full tap array (SGPRs), no ring hazard
        #pragma unroll
        for (int kh = 6; kh >= 5; --kh)                 // prologue: kh used at rr=0,1
            #pragma unroll
            for (int i2 = 0; i2 < 8; ++i2) kv[kh][i2] = tkt[kh * 8 + i2];

        #pragma unroll
        for (int rr = 0; rr < 10; ++rr) {
            if (rr <= 4) {                              // prefetch kh=4-rr (first use at rr+2)
                const int kh = 4 - rr;
                #pragma unroll
                for (int i2 = 0; i2 < 8; ++i2) kv[kh][i2] = tkt[kh * 8 + i2];
            }
            const int gh = (h0 - 3 + 4 * iy + rr) & 63;
            const int rowu = gh * 64;
            uint row[12];
            #pragma unroll
            for (int m = 0; m < 3; ++m) {
                const uint4 v = *reinterpret_cast<const uint4*>(pin + rowu + colu[m]);
                row[4 * m]     = v.x; row[4 * m + 1] = v.y;
                row[4 * m + 2] = v.z; row[4 * m + 3] = v.w;
            }
            #pragma unroll
            for (int o = 0; o < 4; ++o) {
                const int kh = o + 6 - rr;
                if (kh < 0 || kh > 6) continue;
                #pragma unroll
                for (int kw = 0; kw < 7; ++kw)
                    #pragma unroll
                    for (int j = 0; j < 4; ++j)
                        pk_fma_sv(tot[o][j], kv[kh][kw], row[j + 7 - kw]);
            }
        }
    }

    uint* ob = out + pair * 262144 + (b * 32 + t) * 4096;
    #pragma unroll
    for (int o = 0; o < 4; ++o)
        *reinterpret_cast<uint4*>(ob + (h0 + 4 * iy + o) * 64 + (w0 + 4 * ix)) =
            make_uint4(tot[o][0], tot[o][1], tot[o][2], tot[o][3]);
}

// ---------------- minGRU scan over T (f32 math, channel-major h2 I/O) ----------------
__global__ __launch_bounds__(256) void scan_kernel(
    const uint* __restrict__ gs, const uint* __restrict__ hs, uint* __restrict__ hout)
{
    const int tid = blockIdx.x * 256 + threadIdx.x;    // 0..262143
    const int base = (tid >> 12) * 131072 + (tid & 4095);
    float h0 = 0.f, h1 = 0.f;
    for (int t = 0; t < 32; ++t) {
        const int a = base + t * 4096;
        const float2 g  = __half22float2(__builtin_bit_cast(__half2, gs[a]));
        const float2 hv = __half22float2(__builtin_bit_cast(__half2, hs[a]));
        const float z0 = 1.f / (1.f + __expf(-g.x));
        const float z1 = 1.f / (1.f + __expf(-g.y));
        h0 = fmaf(1.f - z0, h0, z0 * fmaf(hv.x, hv.x, 1e-6f));
        h1 = fmaf(1.f - z1, h1, z1 * fmaf(hv.y, hv.y, 1e-6f));
        hout[a] = __builtin_bit_cast(uint, __floats2half2_rn(h0, h1));
    }
}

// ---------------- output GEMM (MFMA f16, channel-major in, f32 row-major out) ----------------
__global__ __launch_bounds__(256) void outgemm_kernel(
    const uint* __restrict__ hin, const float* __restrict__ w,
    const float* __restrict__ bias, float* __restrict__ out)
{
    __shared__ __align__(16) uint sXu[128 * 36];        // rows x 32 pairs (stride 36: 16B-aligned)
    __shared__ __align__(16) _Float16 sWT[64 * 64];
    const int tid = threadIdx.x;
    const int row0 = (int)blockIdx.x * 128;

    {   // stage 128 rows x 32 pairs from channel-major
        const int pr = tid >> 3, k = tid & 7;
        const uint* src = hin + pr * 262144 + row0 + k * 16;
        #pragma unroll
        for (int q = 0; q < 4; ++q) {
            const uint4 v = *reinterpret_cast<const uint4*>(src + q * 4);
            sXu[(k * 16 + q * 4 + 0) * 36 + pr] = v.x;
            sXu[(k * 16 + q * 4 + 1) * 36 + pr] = v.y;
            sXu[(k * 16 + q * 4 + 2) * 36 + pr] = v.z;
            sXu[(k * 16 + q * 4 + 3) * 36 + pr] = v.w;
        }
    }
    {
        const int d = tid & 63;
        const int cb = (tid >> 6) * 16;
        #pragma unroll
        for (int i = 0; i < 16; ++i) {
            const int c = cb + i;
            sWT[d * 64 + (((c >> 3) ^ (d & 7)) * 8) + (c & 7)] = (_Float16)w[c * 64 + d];
        }
    }
    __syncthreads();

    const int wv = tid >> 6, lm = tid & 15, lg = (tid & 63) >> 4;
    f16x8 bf[4][2];
    #pragma unroll
    for (int nt = 0; nt < 4; ++nt) {
        const int d = nt * 16 + lm;
        #pragma unroll
        for (int s = 0; s < 2; ++s)
            bf[nt][s] = *reinterpret_cast<const f16x8*>(&sWT[d * 64 + (((s * 4 + lg) ^ (d & 7)) * 8)]);
    }
    f32x4 acc[2][4];
    #pragma unroll
    for (int mt = 0; mt < 2; ++mt)
        #pragma unroll
        for (int nt = 0; nt < 4; ++nt)
            acc[mt][nt] = (f32x4){0.f, 0.f, 0.f, 0.f};

    #pragma unroll
    for (int mt = 0; mt < 2; ++mt) {
        const int r = wv * 32 + mt * 16 + lm;
        const f16x8 a0 = *reinterpret_cast<const f16x8*>(&sXu[r * 36 + lg * 4]);
        const f16x8 a1 = *reinterpret_cast<const f16x8*>(&sXu[r * 36 + 16 + lg * 4]);
        #pragma unroll
        for (int nt = 0; nt < 4; ++nt) {
            acc[mt][nt] = __builtin_amdgcn_mfma_f32_16x16x32_f16(a0, bf[nt][0], acc[mt][nt], 0, 0, 0);
            acc[mt][nt] = __builtin_amdgcn_mfma_f32_16x16x32_f16(a1, bf[nt][1], acc[mt][nt], 0, 0, 0);
        }
    }
    #pragma unroll
    for (int nt = 0; nt < 4; ++nt) {
        const int col = nt * 16 + lm;
        const float bv = bias[col];
        #pragma unroll
        for (int mt = 0; mt < 2; ++mt) {
            const long long rb = row0 + wv * 32 + mt * 16 + lg * 4;
            #pragma unroll
            for (int i = 0; i < 4; ++i)
                out[(rb + i) * 64 + col] = acc[mt][nt][i] + bv;
        }
    }
}

extern "C" void kernel_launch(void* const* d_in, const int* in_sizes, int n_in,
                              void* d_out, int out_size, void* d_ws, size_t ws_size,
                              hipStream_t stream)
{
    const float* x  = (const float*)d_in[0];
    const float* gw = (const float*)d_in[1];
    const float* gb = (const float*)d_in[2];
    const float* hw = (const float*)d_in[3];
    const float* hb = (const float*)d_in[4];
    const float* gk = (const float*)d_in[5];
    const float* hk = (const float*)d_in[6];
    const float* ow = (const float*)d_in[7];
    const float* ob = (const float*)d_in[8];

    uint* W1 = (uint*)d_ws;                  // 33.5 MB each (channel-major h2)
    uint* W2 = W1 + NELEM / 2;
    uint* W3 = W2 + NELEM / 2;
    uint* taps = W3 + NELEM / 2;             // 71.7 KB tap table
    uint* Dsc = (uint*)d_out;                // hidden_spatial scratch (first 33.5MB of d_out)

    // 0) tap table
    tapconv_kernel<<<70, 256, 0, stream>>>(gk, hk, taps);
    // 1) proj: x -> W1 (gate_proj cm), W2 (hidden_proj cm)
    proj2_kernel<<<2048, 256, 0, stream>>>(x, gw, gb, hw, hb, W1, W2);
    // 2+3) dual conv (LDS-free): W1 -> W3 (gate_sp), W2 -> Dsc (hidden_sp)
    conv3d_dual_kernel<<<4096, 256, 0, stream>>>(W1, W3, W2, Dsc, taps);
    // 4) scan: (W3, Dsc) -> W1 (h, cm)
    scan_kernel<<<1024, 256, 0, stream>>>(W3, Dsc, W1);
    // 5) out GEMM: W1 -> d_out (f32 row-major, overwrites scratch)
    outgemm_kernel<<<2048, 256, 0, stream>>>(W1, ow, ob, (float*)d_out);
}